// Round 4
// baseline (1081.410 us; speedup 1.0000x reference)
//
#include <hip/hip_runtime.h>
#include <hip/hip_cooperative_groups.h>
#include <cstdint>
#include <cstddef>

namespace cg = cooperative_groups;

typedef _Float16 half8  __attribute__((ext_vector_type(8)));
typedef _Float16 half4v __attribute__((ext_vector_type(4)));
typedef float    f32x4  __attribute__((ext_vector_type(4)));

static constexpr int HWPX = 1024;
static constexpr int NPX  = 16384;
static constexpr int DBB  = 768;
static constexpr int DD   = 512;
static constexpr int KC   = 201;
static constexpr int KM   = 2010;   // KC * 10
static constexpr int KMP  = 2048;   // padded

// ---- workspace offsets (bytes) ----
static constexpr size_t OFF_MEANP  = 0;        // [8][768] f64 partials
static constexpr size_t OFF_XCH    = 49152;    // [10][8][768] f64 iterate partials
static constexpr size_t OFF_ROW16  = 540672;   // [16][2016] f32
static constexpr size_t OFF_ROW3   = 669696;   // [2016] f32
static constexpr size_t OFF_ROW5   = 677760;   // [2016] f32
static constexpr size_t OFF_BK     = 685824;   // 256 i32
static constexpr size_t OFF_NCNT   = 686848;   // 2016 i32
static constexpr size_t OFF_MM     = 694912;   // 2 f64
static constexpr size_t OFF_PMM    = 694928;   // [512][2] f64 block minmax partials
static constexpr size_t OFF_FPROTO = 703488;   // 2010*512 f32
static constexpr size_t ZTOTAL     = 4819968;  // single memset covers all above
static constexpr size_t OFF_GTSEG  = 4849664;  // 16384 i32
static constexpr size_t OFF_CORR   = 4915200;  // 16384 i32
static constexpr size_t OFF_U      = 4980736;  // 16384 f64
static constexpr size_t OFF_PN     = 5111808;  // 2010*512 f32
static constexpr size_t OFF_P16    = 9228288;  // 2048*512 f16
static constexpr size_t OFF_C16    = 11325440; // 16384*512 f16
static constexpr size_t OFF_QD     = 28102656; // 16384*10 f32
static constexpr size_t OFF_W16    = 28758016; // 512*768 f16

// ---- d_out offsets (floats) ----
static constexpr size_t OUT_SEG = 0;
static constexpr size_t OUT_PL  = 3293184;
static constexpr size_t OUT_PT  = 36225024;
static constexpr size_t OUT_PG  = 36241408;
static constexpr size_t OUT_NP  = 36257792;

#define GLDS16(gp, lp) __builtin_amdgcn_global_load_lds( \
    (__attribute__((address_space(1))) const void*)(gp), \
    (__attribute__((address_space(3))) void*)(lp), 16, 0, 0)

static __device__ __forceinline__ float  wredf(float x){
  #pragma unroll
  for (int o=32;o;o>>=1) x += __shfl_down(x,o);
  return x;
}
static __device__ __forceinline__ double wredd(double x){
  #pragma unroll
  for (int o=32;o;o>>=1) x += __shfl_down(x,o);
  return x;
}

// ================= cooperative PCA: colsum + 10 power iters + u + minmax + pseudo =================
// 512 blocks x 256 threads, 32 rows/block (8 per wave). Un-normalized f64 power iteration
// (direction-equivalent; iterates peak ~1e44 << f64 range; Us is scale-invariant).
__global__ __launch_bounds__(256, 2) void kPCAcoop(const float* __restrict__ A, const int* __restrict__ gt,
    double* __restrict__ meanp, double* __restrict__ xch, double* __restrict__ u,
    double* __restrict__ mm, double* __restrict__ pmm,
    float* __restrict__ outPG, int* __restrict__ gtseg, int* __restrict__ Bk){
  cg::grid_group grid = cg::this_grid();
  __shared__ double vs[768], ms[768];
  __shared__ double red[4][12][64];
  __shared__ double sA[16];
  const int tid = threadIdx.x;
  const int lane = tid & 63, w = tid >> 6;
  const int bid = blockIdx.x;
  const int rbase = bid*32 + w*8;

  // ---- phase 0: column sums -> meanp partials ----
  {
    double acc[12];
    #pragma unroll
    for (int j=0;j<12;j++) acc[j]=0.0;
    for (int i=0;i<8;i++){
      const float* Ar = A + (size_t)(rbase+i)*DBB;
      #pragma unroll
      for (int j=0;j<12;j++) acc[j] += (double)Ar[j*64+lane];
    }
    #pragma unroll
    for (int j=0;j<12;j++) red[w][j][lane] = acc[j];
    __syncthreads();
    double* dst = meanp + (size_t)(bid&7)*768;
    for (int cc=tid; cc<768; cc+=256){
      int j = cc>>6, l = cc&63;
      atomicAdd(&dst[cc], red[0][j][l]+red[1][j][l]+red[2][j][l]+red[3][j][l]);
    }
  }
  grid.sync();

  // ---- phases 1..10: y = Ac^T (Ac x) ----
  for (int t=0;t<10;t++){
    const double* xp = (t==0)? nullptr : (xch + (size_t)(t-1)*8*768);
    double* y = xch + (size_t)t*8*768;
    for (int cc=tid; cc<768; cc+=256){
      double sm=0.0;
      #pragma unroll
      for (int p=0;p<8;p++) sm += meanp[p*768+cc];
      ms[cc] = sm * (1.0/16384.0);
      if (xp){
        double sv=0.0;
        #pragma unroll
        for (int p=0;p<8;p++) sv += xp[p*768+cc];
        vs[cc] = sv;
      } else {
        vs[cc] = 1.0/sqrt(768.0);
      }
    }
    __syncthreads();
    double acc[12];
    #pragma unroll
    for (int j=0;j<12;j++) acc[j]=0.0;
    for (int i=0;i<8;i++){
      const float* Ar = A + (size_t)(rbase+i)*DBB;
      double ad[12]; double wp = 0.0;
      #pragma unroll
      for (int j=0;j<12;j++){ int c=j*64+lane; ad[j] = (double)Ar[c]-ms[c]; wp += ad[j]*vs[c]; }
      wp = wredd(wp); wp = __shfl(wp, 0);
      #pragma unroll
      for (int j=0;j<12;j++) acc[j] += wp*ad[j];
    }
    #pragma unroll
    for (int j=0;j<12;j++) red[w][j][lane] = acc[j];
    __syncthreads();
    double* dst = y + (size_t)(bid&7)*768;
    for (int cc=tid; cc<768; cc+=256){
      int j = cc>>6, l = cc&63;
      atomicAdd(&dst[cc], red[0][j][l]+red[1][j][l]+red[2][j][l]+red[3][j][l]);
    }
    grid.sync();
  }

  // ---- phase 11: u = Ac v ----
  {
    const double* vp = xch + (size_t)9*8*768;
    for (int cc=tid; cc<768; cc+=256){
      double sm=0.0, sv=0.0;
      #pragma unroll
      for (int p=0;p<8;p++){ sm += meanp[p*768+cc]; sv += vp[p*768+cc]; }
      ms[cc] = sm * (1.0/16384.0);
      vs[cc] = sv;
    }
    __syncthreads();
    for (int i=0;i<8;i++){
      const float* Ar = A + (size_t)(rbase+i)*DBB;
      double wp=0.0;
      #pragma unroll
      for (int j=0;j<12;j++){ int c=j*64+lane; wp += ((double)Ar[c]-ms[c])*vs[c]; }
      wp = wredd(wp);
      if (lane==0) u[rbase+i] = wp;
    }
  }
  grid.sync();

  // ---- phase 12: per-block minmax partials ----
  {
    double x = (tid<32)? u[bid*32+tid] : u[bid*32];
    double mn = x, mx = x;
    #pragma unroll
    for (int o=32;o;o>>=1){ mn=fmin(mn,__shfl_down(mn,o)); mx=fmax(mx,__shfl_down(mx,o)); }
    if ((tid&63)==0){ sA[(tid>>6)*2]=mn; sA[(tid>>6)*2+1]=mx; }
    __syncthreads();
    if (tid==0){
      for (int i2=1;i2<4;i2++){ mn=fmin(mn,sA[i2*2]); mx=fmax(mx,sA[i2*2+1]); }
      pmm[bid*2]=mn; pmm[bid*2+1]=mx;
    }
  }
  grid.sync();
  if (bid==0){
    double mn = fmin(pmm[tid*2],   pmm[(tid+256)*2]);
    double mx = fmax(pmm[tid*2+1], pmm[(tid+256)*2+1]);
    #pragma unroll
    for (int o=32;o;o>>=1){ mn=fmin(mn,__shfl_down(mn,o)); mx=fmax(mx,__shfl_down(mx,o)); }
    __syncthreads();   // sA reuse hazard guard
    if ((tid&63)==0){ sA[(tid>>6)*2]=mn; sA[(tid>>6)*2+1]=mx; }
    __syncthreads();
    if (tid==0){
      for (int i2=1;i2<4;i2++){ mn=fmin(mn,sA[i2*2]); mx=fmax(mx,sA[i2*2+1]); }
      mm[0]=mn; mm[1]=mx;
    }
  }
  grid.sync();

  // ---- phase 13: pseudo-gt + Bk ----
  if (tid < 32){
    int n = bid*32 + tid;
    int b = n >> 10;
    double us = (u[n]-mm[0])/(mm[1]-mm[0]);
    int c0g = gt[b];
    int g = (us < 0.5) ? c0g : 200;
    outPG[n] = (float)g;
    gtseg[n] = g;
    unsigned long long b0 = __ballot(g==c0g);
    unsigned long long b1 = __ballot(g==200);
    if (tid==0){
      atomicAdd(&Bk[c0g], (int)__popcll(b0));
      atomicAdd(&Bk[200], (int)__popcll(b1));
    }
  }
}

// ================= prep: W f32->f16 (blocks 0..383) + proto l2-normalize (blocks 384..895) =================
__global__ __launch_bounds__(256) void kPrep(const float* __restrict__ Wp, _Float16* __restrict__ W16,
    const float* __restrict__ PR, float* __restrict__ Pn, _Float16* __restrict__ P16){
  int b = blockIdx.x;
  if (b < 384){
    int i = b*256 + threadIdx.x;           // 384*256 = 98304 = 512*768/4 exact
    float4 vv = ((const float4*)Wp)[i];
    half4v h; h[0]=(_Float16)vv.x; h[1]=(_Float16)vv.y; h[2]=(_Float16)vv.z; h[3]=(_Float16)vv.w;
    ((half4v*)W16)[i] = h;
    return;
  }
  int w=threadIdx.x>>6, lane=threadIdx.x&63;
  int km = (b-384)*4 + w;
  if (km >= KM){
    if (km < KMP){
      half8 z;
      #pragma unroll
      for (int i=0;i<8;i++) z[i]=(_Float16)0.0f;
      *(half8*)(P16 + (size_t)km*DD + lane*8) = z;
    }
    return;
  }
  const float* r = PR + (size_t)km*DD + lane*8;
  float4 a = *(const float4*)r, b2 = *(const float4*)(r+4);
  float x[8] = {a.x,a.y,a.z,a.w,b2.x,b2.y,b2.z,b2.w};
  float ss=0;
  #pragma unroll
  for (int i=0;i<8;i++) ss += x[i]*x[i];
  ss = __shfl(wredf(ss),0);
  float nrm = fmaxf(sqrtf(ss), 1e-12f);
  float* pw = Pn + (size_t)km*DD + lane*8;
  half8 h;
  #pragma unroll
  for (int i=0;i<8;i++){ float vv = x[i]/nrm; pw[i]=vv; h[i]=(_Float16)vv; }
  *(half8*)(P16 + (size_t)km*DD + lane*8) = h;
}

// ================= GEMM1: C16[16384,512] = f16( A_f32[16384,768] @ W16^T + b ) =================
// A read in f32, converted to f16 during reg-staged swizzled ds_write; B via global_load_lds.
__global__ __launch_bounds__(256) void gemm1(const float* __restrict__ Af, const _Float16* __restrict__ Bm,
    _Float16* __restrict__ Ch, const float* __restrict__ bias){
  __shared__ __align__(16) char As[128*128];
  __shared__ __align__(16) char Bs[128*128];
  const int tid = threadIdx.x;
  const int lane = tid & 63, w = tid >> 6;
  const int wr = w >> 1, wc = w & 1;
  const int lrow = lane & 15, kg = lane >> 4;
  // XCD-chunked swizzle: 512 blocks -> each XCD owns contiguous 16 M-tiles x 4 N-tiles
  const int id = blockIdx.x;
  const int xcd = id & 7, pos = id >> 3;
  const int m0 = ((xcd<<4) | (pos>>2)) * 128;
  const int n0 = (pos & 3) * 128;

  f32x4 acc[4][4];
  #pragma unroll
  for (int i=0;i<4;i++)
    #pragma unroll
    for (int j=0;j<4;j++){ f32x4 z = {0.f,0.f,0.f,0.f}; acc[i][j]=z; }

  for (int k0 = 0; k0 < DBB; k0 += 64){
    #pragma unroll
    for (int i=0;i<4;i++){
      int slot = (i*4 + w)*64 + lane;
      int r = slot >> 3, c = slot & 7;
      int cs = c ^ (r & 7);
      GLDS16(Bm + (size_t)(n0+r)*DBB + k0 + cs*8, Bs + (i*4+w)*1024);
    }
    #pragma unroll
    for (int i=0;i<8;i++){
      int slot = i*256 + tid;            // 0..2047
      int r = slot >> 4, c4 = slot & 15; // 16 float4 per row
      float4 v = *(const float4*)(Af + (size_t)(m0+r)*DBB + k0 + c4*4);
      half4v h; h[0]=(_Float16)v.x; h[1]=(_Float16)v.y; h[2]=(_Float16)v.z; h[3]=(_Float16)v.w;
      *(half4v*)(As + r*128 + (((c4>>1)^(r&7))<<4) + (c4&1)*8) = h;
    }
    __syncthreads();
    #pragma unroll
    for (int h=0; h<2; h++){
      half8 af[4], bf[4];
      #pragma unroll
      for (int mi=0;mi<4;mi++){
        int ar = wr*64 + mi*16 + lrow;
        af[mi] = *(const half8*)(As + ar*128 + (((h*4+kg) ^ (ar&7))<<4));
      }
      #pragma unroll
      for (int nj=0;nj<4;nj++){
        int br = wc*64 + nj*16 + lrow;
        bf[nj] = *(const half8*)(Bs + br*128 + (((h*4+kg) ^ (br&7))<<4));
      }
      #pragma unroll
      for (int mi=0;mi<4;mi++)
        #pragma unroll
        for (int nj=0;nj<4;nj++)
          acc[mi][nj] = __builtin_amdgcn_mfma_f32_16x16x32_f16(af[mi], bf[nj], acc[mi][nj], 0,0,0);
    }
    __syncthreads();
  }
  #pragma unroll
  for (int mi=0;mi<4;mi++){
    int gr = m0 + wr*64 + mi*16 + kg*4;
    #pragma unroll
    for (int nj=0;nj<4;nj++){
      int gc = n0 + wc*64 + nj*16 + lrow;
      float bv = bias[gc];
      #pragma unroll
      for (int r2=0;r2<4;r2++)
        Ch[(size_t)(gr+r2)*DD + gc] = (_Float16)(acc[mi][nj][r2] + bv);
    }
  }
}

// ================= GEMM2: PL[16384,2010] = _c @ protos^T (fp16 MFMA, f32 out) =================
__global__ __launch_bounds__(256) void gemm2(const _Float16* __restrict__ Am, const _Float16* __restrict__ Bm,
    float* __restrict__ Cf){
  __shared__ __align__(16) char As[128*128];
  __shared__ __align__(16) char Bs[128*128];
  const int tid = threadIdx.x;
  const int lane = tid & 63, w = tid >> 6;
  const int wr = w >> 1, wc = w & 1;
  const int lrow = lane & 15, kg = lane >> 4;
  // XCD-chunked swizzle: 2048 blocks; each XCD: 16 M-tiles x 16 N-tiles contiguous
  const int id = blockIdx.x;
  const int xcd = id & 7, pos = id >> 3;
  const int m0 = ((xcd<<4) | (pos>>4)) * 128;
  const int n0 = (pos & 15) * 128;

  f32x4 acc[4][4];
  #pragma unroll
  for (int i=0;i<4;i++)
    #pragma unroll
    for (int j=0;j<4;j++){ f32x4 z = {0.f,0.f,0.f,0.f}; acc[i][j]=z; }

  for (int k0 = 0; k0 < DD; k0 += 64){
    #pragma unroll
    for (int i=0;i<4;i++){
      int slot = (i*4 + w)*64 + lane;
      int r = slot >> 3, c = slot & 7;
      int cs = c ^ (r & 7);
      GLDS16(Am + (size_t)(m0+r)*DD + k0 + cs*8, As + (i*4+w)*1024);
      GLDS16(Bm + (size_t)(n0+r)*DD + k0 + cs*8, Bs + (i*4+w)*1024);
    }
    __syncthreads();
    #pragma unroll
    for (int h=0; h<2; h++){
      half8 af[4], bf[4];
      #pragma unroll
      for (int mi=0;mi<4;mi++){
        int ar = wr*64 + mi*16 + lrow;
        af[mi] = *(const half8*)(As + ar*128 + (((h*4+kg) ^ (ar&7))<<4));
      }
      #pragma unroll
      for (int nj=0;nj<4;nj++){
        int br = wc*64 + nj*16 + lrow;
        bf[nj] = *(const half8*)(Bs + br*128 + (((h*4+kg) ^ (br&7))<<4));
      }
      #pragma unroll
      for (int mi=0;mi<4;mi++)
        #pragma unroll
        for (int nj=0;nj<4;nj++)
          acc[mi][nj] = __builtin_amdgcn_mfma_f32_16x16x32_f16(af[mi], bf[nj], acc[mi][nj], 0,0,0);
    }
    __syncthreads();
  }
  #pragma unroll
  for (int mi=0;mi<4;mi++){
    int gr = m0 + wr*64 + mi*16 + kg*4;
    #pragma unroll
    for (int nj=0;nj<4;nj++){
      int gc = n0 + wc*64 + nj*16 + lrow;
      if (gc < KM){
        #pragma unroll
        for (int r2=0;r2<4;r2++)
          Cf[(size_t)(gr+r2)*KM + gc] = acc[mi][nj][r2];
      }
    }
  }
}

// ================= LN + l2 normalize (in-place on C16) =================
__global__ __launch_bounds__(256) void kLNl2n(_Float16* __restrict__ C16,
      const float* __restrict__ fg, const float* __restrict__ fb){
  int w=threadIdx.x>>6, lane=threadIdx.x&63;
  int n = blockIdx.x*4 + w;
  _Float16* row = C16 + (size_t)n*DD + lane*8;
  half8 h = *(const half8*)row;
  float x[8];
  #pragma unroll
  for (int i=0;i<8;i++) x[i] = (float)h[i];
  float s=0;
  #pragma unroll
  for (int i=0;i<8;i++) s += x[i];
  float mu = __shfl(wredf(s),0)/512.f;
  float q=0;
  #pragma unroll
  for (int i=0;i<8;i++){ float d=x[i]-mu; q+=d*d; }
  float var = __shfl(wredf(q),0)/512.f;
  float inv = 1.f/sqrtf(var+1e-5f);
  float4 g0 = *(const float4*)(fg+lane*8), g1 = *(const float4*)(fg+lane*8+4);
  float4 b0 = *(const float4*)(fb+lane*8), b1 = *(const float4*)(fb+lane*8+4);
  float gg[8] = {g0.x,g0.y,g0.z,g0.w,g1.x,g1.y,g1.z,g1.w};
  float bb[8] = {b0.x,b0.y,b0.z,b0.w,b1.x,b1.y,b1.z,b1.w};
  float y[8]; float ss=0;
  #pragma unroll
  for (int i=0;i<8;i++){ y[i] = (x[i]-mu)*inv*gg[i]+bb[i]; ss += y[i]*y[i]; }
  float nrm = fmaxf(sqrtf(__shfl(wredf(ss),0)), 1e-12f);
  half8 o;
  #pragma unroll
  for (int i=0;i<8;i++) o[i] = (_Float16)(y[i]/nrm);
  *(half8*)row = o;
}

// ================= fused per-class max + mask LN + pred + transpose-out =================
__global__ __launch_bounds__(256) void kMaxLNT(const float* __restrict__ PL, const float* __restrict__ mg,
    const float* __restrict__ mb, const int* __restrict__ gtseg,
    float* __restrict__ outseg, int* __restrict__ corr){
  __shared__ float rowb[4][2016];
  __shared__ float tile[32][205];
  int w=threadIdx.x>>6, lane=threadIdx.x&63;
  int n0 = blockIdx.x*32;
  int b = n0>>10, hw0 = n0&1023;
  for (int g8=0; g8<8; ++g8){
    int n = n0 + g8*4 + w;
    const float* src = PL + (size_t)n*KM;
    for (int j2=lane;j2<1005;j2+=64)
      *(float2*)(&rowb[w][j2*2]) = *(const float2*)(src + j2*2);
    float xv[4]; int ncl=0;
    for (int c=lane;c<KC;c+=64){
      float mx = rowb[w][c*10];
      #pragma unroll
      for (int m=1;m<10;m++) mx = fmaxf(mx, rowb[w][c*10+m]);
      xv[ncl++] = mx;
    }
    float ps=0;
    for (int i=0;i<ncl;i++) ps += xv[i];
    float mu = __shfl(wredf(ps),0)*(1.f/201.f);
    float pv=0;
    for (int i=0;i<ncl;i++){ float d=xv[i]-mu; pv+=d*d; }
    float var = __shfl(wredf(pv),0)*(1.f/201.f);
    float inv = 1.f/sqrtf(var+1e-5f);
    float bv = -3.0e38f; int bi = 1<<30;
    int lr = g8*4 + w;
    ncl = 0;
    for (int c=lane;c<KC;c+=64){
      float o = (xv[ncl]-mu)*inv*mg[c]+mb[c]; ncl++;
      tile[lr][c] = o;
      if (o > bv){ bv=o; bi=c; }
    }
    #pragma unroll
    for (int o2=32;o2;o2>>=1){
      float ov = __shfl_down(bv,o2); int oi = __shfl_down(bi,o2);
      if (ov>bv || (ov==bv && oi<bi)){ bv=ov; bi=oi; }
    }
    if (lane==0) corr[n] = (bi==gtseg[n]) ? 1 : 0;
  }
  __syncthreads();
  for (int idx=threadIdx.x; idx<KC*32; idx+=256){
    int c = idx>>5, j = idx&31;
    outseg[(((size_t)b*KC+c)<<10) + hw0 + j] = tile[j][c];
  }
}

// ================= sinkhorn: gather Qd from PL + row-sum partials =================
__global__ __launch_bounds__(256) void kSKgRow(const float* __restrict__ PL, const int* __restrict__ gtseg,
      const int* __restrict__ gt, float* __restrict__ Qd, float* __restrict__ row16){
  __shared__ double part[4][10][2];
  int n = blockIdx.x*256+threadIdx.x;
  int g = gtseg[n];
  int c0 = gt[blockIdx.x>>2];
  int w=threadIdx.x>>6, lane=threadIdx.x&63;
  const float* src = PL + (size_t)n*KM + g*10;
  float e[10];
  #pragma unroll
  for (int m2=0;m2<5;m2++){
    float2 v = *(const float2*)(src + m2*2);
    e[m2*2]   = expf(v.x*20.f);
    e[m2*2+1] = expf(v.y*20.f);
  }
  float* qdst = Qd + (size_t)n*10;
  #pragma unroll
  for (int m2=0;m2<5;m2++){
    float2 v; v.x=e[m2*2]; v.y=e[m2*2+1];
    *(float2*)(qdst + m2*2) = v;
  }
  #pragma unroll
  for (int m=0;m<10;m++){
    double p0 = (g==c0)? (double)e[m]:0.0;
    double p1 = (g==200)? (double)e[m]:0.0;
    p0=wredd(p0); p1=wredd(p1);
    if (lane==0){ part[w][m][0]=p0; part[w][m][1]=p1; }
  }
  __syncthreads();
  if (threadIdx.x < 20){
    int m = threadIdx.x>>1, cl = threadIdx.x&1;
    double t = part[0][m][cl]+part[1][m][cl]+part[2][m][cl]+part[3][m][cl];
    atomicAdd(&row16[(size_t)(blockIdx.x&15)*2016 + m*KC + (cl?200:c0)], (float)t);
  }
}

// one sinkhorn iteration; rin has rin_parts partial buffers of stride 2016
__global__ __launch_bounds__(256) void kSKpass(float* __restrict__ Qd, const int* __restrict__ gtseg,
      const int* __restrict__ gt, const float* __restrict__ rin, int rin_parts,
      float* __restrict__ rout, const int* __restrict__ Bk){
  __shared__ float rin2[10][2];
  __shared__ double part[4][10][2];
  int n = blockIdx.x*256+threadIdx.x;
  int c0 = gt[blockIdx.x>>2];
  if (threadIdx.x < 20){
    int m = threadIdx.x>>1, cl = threadIdx.x&1;
    int cls = cl?200:c0;
    float s=0;
    for (int p=0;p<rin_parts;p++) s += rin[(size_t)p*2016 + m*KC + cls];
    rin2[m][cl]=s;
  }
  __syncthreads();
  int g = gtseg[n];
  int cl = (g==200)?1:0;
  double q[10]; double col=0.0;
  #pragma unroll
  for (int m=0;m<10;m++){
    double r = (double)rin2[m][cl];
    double t = (double)Qd[(size_t)n*10+m];
    if (r>0.0) t = t/r;
    t = t/10.0;
    q[m]=t; col+=t;
  }
  double cs = (col>0.0)? col : 1.0;
  int bk = Bk[g];
  double bs = (bk>0)? (double)bk : 1.0;
  double inv = 1.0/(cs*bs);
  int w=threadIdx.x>>6, lane=threadIdx.x&63;
  #pragma unroll
  for (int m=0;m<10;m++){
    double t = q[m]*inv;
    Qd[(size_t)n*10+m] = (float)t;
    double p0 = (g==c0)? t:0.0;
    double p1 = (g==200)? t:0.0;
    p0=wredd(p0); p1=wredd(p1);
    if (lane==0){ part[w][m][0]=p0; part[w][m][1]=p1; }
  }
  __syncthreads();
  if (threadIdx.x < 20){
    int m = threadIdx.x>>1, cl2 = threadIdx.x&1;
    double t = part[0][m][cl2]+part[1][m][cl2]+part[2][m][cl2]+part[3][m][cl2];
    atomicAdd(&rout[m*KC + (cl2?200:c0)], (float)t);
  }
}

// fused final argmax + proto_target write + EMA accumulation (wave per pixel)
__global__ __launch_bounds__(256) void kSKEMA(const float* __restrict__ Qd, const int* __restrict__ gtseg,
      const float* __restrict__ r5, const int* __restrict__ corr, const _Float16* __restrict__ C16,
      float* __restrict__ outPT, float* __restrict__ fproto, int* __restrict__ ncnt){
  int w=threadIdx.x>>6, lane=threadIdx.x&63;
  int n = blockIdx.x*4+w;
  int g = gtseg[n];
  float tv = -1.0f;
  if (lane<10){
    float r = r5[lane*KC+g];
    float t = Qd[(size_t)n*10+lane];
    if (r>0.f) t = t/r;
    tv = t*0.1f;
  }
  float bv = tv; int bi = lane;
  #pragma unroll
  for (int o=8;o;o>>=1){
    float ov = __shfl_down(bv,o); int oi = __shfl_down(bi,o);
    if (ov>bv || (ov==bv && oi<bi)){ bv=ov; bi=oi; }
  }
  bi = __shfl(bi, 0);
  if (lane==0) outPT[n] = (float)(bi + 10*g);
  if (corr[n]){
    half8 hc = *(const half8*)(C16 + (size_t)n*DD + lane*8);
    float* dst = fproto + ((size_t)g*10+bi)*DD + lane*8;
    #pragma unroll
    for (int i=0;i<8;i++) atomicAdd(dst+i, (float)hc[i]);
    if (lane==0) atomicAdd(&ncnt[g*10+bi], 1);
  }
}

__global__ __launch_bounds__(256) void kEMAfin(const float* __restrict__ fproto, const int* __restrict__ ncnt,
     const float* __restrict__ Pn, float* __restrict__ outNP){
  int w=threadIdx.x>>6, lane=threadIdx.x&63;
  int km = blockIdx.x*4+w;
  if (km>=KM) return;
  const float* fr = fproto + (size_t)km*DD + lane*8;
  float fp[8]; float ss=0;
  #pragma unroll
  for (int i=0;i<8;i++){ fp[i]=fr[i]; ss+=fp[i]*fp[i]; }
  float n1 = fmaxf(sqrtf(__shfl(wredf(ss),0)), 1e-12f);
  int cnt = ncnt[km];
  const float* pr = Pn + (size_t)km*DD + lane*8;
  float t[8]; float s2=0;
  #pragma unroll
  for (int i=0;i<8;i++){
    float pv = pr[i];
    float tv = cnt ? (0.999f*pv + 0.001f*(fp[i]/n1)) : pv;
    t[i]=tv; s2+=tv*tv;
  }
  float n2 = fmaxf(sqrtf(__shfl(wredf(s2),0)), 1e-12f);
  float* dst = outNP + (size_t)km*DD + lane*8;
  #pragma unroll
  for (int i=0;i<8;i++) dst[i] = t[i]/n2;
}

// ================= launch =================
extern "C" void kernel_launch(void* const* d_in, const int* in_sizes, int n_in,
                              void* d_out, int out_size, void* d_ws, size_t ws_size,
                              hipStream_t stream) {
  const float* A   = (const float*)d_in[0];
  const int*   gt  = (const int*)d_in[1];
  const float* Wp  = (const float*)d_in[2];
  const float* pb  = (const float*)d_in[3];
  const float* fg  = (const float*)d_in[4];
  const float* fb  = (const float*)d_in[5];
  const float* mg  = (const float*)d_in[6];
  const float* mb  = (const float*)d_in[7];
  const float* PR  = (const float*)d_in[8];
  float* out = (float*)d_out;
  char* ws = (char*)d_ws;

  double* meanp  = (double*)(ws+OFF_MEANP);
  double* xch    = (double*)(ws+OFF_XCH);
  float*  row16  = (float*)(ws+OFF_ROW16);
  float*  row3   = (float*)(ws+OFF_ROW3);
  float*  row5   = (float*)(ws+OFF_ROW5);
  int*    Bk     = (int*)(ws+OFF_BK);
  int*    ncnt   = (int*)(ws+OFF_NCNT);
  double* mm     = (double*)(ws+OFF_MM);
  double* pmm    = (double*)(ws+OFF_PMM);
  float*  fproto = (float*)(ws+OFF_FPROTO);
  int*    gtseg  = (int*)(ws+OFF_GTSEG);
  int*    corr   = (int*)(ws+OFF_CORR);
  double* u      = (double*)(ws+OFF_U);
  float*  Pn     = (float*)(ws+OFF_PN);
  _Float16* P16  = (_Float16*)(ws+OFF_P16);
  _Float16* C16  = (_Float16*)(ws+OFF_C16);
  float*  Qd     = (float*)(ws+OFF_QD);
  _Float16* W16  = (_Float16*)(ws+OFF_W16);

  // single memset: all accumulators
  hipMemsetAsync(ws, 0, ZTOTAL, stream);

  // ---- cooperative PCA + pseudo-gt (one launch) ----
  float* outPG = out + OUT_PG;
  void* args[] = {(void*)&A, (void*)&gt, (void*)&meanp, (void*)&xch, (void*)&u,
                  (void*)&mm, (void*)&pmm, (void*)&outPG, (void*)&gtseg, (void*)&Bk};
  hipLaunchCooperativeKernel((void*)kPCAcoop, dim3(512), dim3(256), args, 0, stream);

  // ---- prep: W conv + proto normalize ----
  kPrep<<<896,256,0,stream>>>(Wp, W16, PR, Pn, P16);

  // ---- GEMM1 (f32 A, fused convert) + LN+l2n ----
  gemm1<<<512,256,0,stream>>>(A, W16, C16, pb);
  kLNl2n<<<4096,256,0,stream>>>(C16, fg, fb);

  // ---- GEMM2: proto_logits ----
  gemm2<<<2048,256,0,stream>>>(C16, P16, out+OUT_PL);

  // ---- fused max/LN/pred/transpose ----
  kMaxLNT<<<512,256,0,stream>>>(out+OUT_PL, mg, mb, gtseg, out+OUT_SEG, corr);

  // ---- sinkhorn (gather from PL) ----
  kSKgRow<<<64,256,0,stream>>>(out+OUT_PL, gtseg, gt, Qd, row16);
  kSKpass<<<64,256,0,stream>>>(Qd, gtseg, gt, row16, 16, row3, Bk);
  kSKpass<<<64,256,0,stream>>>(Qd, gtseg, gt, row3, 1, row5, Bk);
  kSKEMA<<<4096,256,0,stream>>>(Qd, gtseg, row5, corr, C16, out+OUT_PT, fproto, ncnt);

  // ---- EMA finalize ----
  kEMAfin<<<503,256,0,stream>>>(fproto, ncnt, Pn, out+OUT_NP);
}

// Round 5
// 394.878 us; speedup vs baseline: 2.7386x; 2.7386x over previous
//
#include <hip/hip_runtime.h>
#include <cstdint>
#include <cstddef>

typedef _Float16 half8  __attribute__((ext_vector_type(8)));
typedef _Float16 half4v __attribute__((ext_vector_type(4)));
typedef float    f32x4  __attribute__((ext_vector_type(4)));

static constexpr int HWPX = 1024;
static constexpr int NPX  = 16384;
static constexpr int DBB  = 768;
static constexpr int DD   = 512;
static constexpr int KC   = 201;
static constexpr int KM   = 2010;   // KC * 10
static constexpr int KMP  = 2048;   // padded

// ---- workspace offsets (bytes) ----
static constexpr size_t OFF_MEANP  = 0;        // [8][768] f64 colsum partials
static constexpr size_t OFF_XCH    = 49152;    // [10][8][768] f64 iterate partials
static constexpr size_t OFF_ROW16  = 540672;   // [16][2016] f32
static constexpr size_t OFF_ROW3   = 669696;   // [2016] f32
static constexpr size_t OFF_ROW5   = 677760;   // [2016] f32
static constexpr size_t OFF_BK     = 685824;   // 256 i32
static constexpr size_t OFF_NCNT   = 686848;   // 2016 i32
static constexpr size_t OFF_FPROTO = 694912;   // 2010*512 f32
static constexpr size_t ZTOTAL     = 4811392;  // single memset covers all above
static constexpr size_t OFF_MSF    = 4811392;  // 768 f64 final mean (written whole by kRedM)
static constexpr size_t OFF_GTSEG  = 4817536;  // 16384 i32
static constexpr size_t OFF_CORR   = 4883072;  // 16384 i32
static constexpr size_t OFF_U      = 4948608;  // 16384 f64
static constexpr size_t OFF_PN     = 5079680;  // 2010*512 f32
static constexpr size_t OFF_P16    = 9196160;  // 2048*512 f16
static constexpr size_t OFF_C16    = 11293312; // 16384*512 f16
static constexpr size_t OFF_QD     = 28070528; // 16384*10 f32
static constexpr size_t OFF_W16    = 28725888; // 512*768 f16 (end ~29.5 MB << ws)

// ---- d_out offsets (floats) ----
static constexpr size_t OUT_SEG = 0;
static constexpr size_t OUT_PL  = 3293184;
static constexpr size_t OUT_PT  = 36225024;
static constexpr size_t OUT_PG  = 36241408;
static constexpr size_t OUT_NP  = 36257792;

#define GLDS16(gp, lp) __builtin_amdgcn_global_load_lds( \
    (__attribute__((address_space(1))) const void*)(gp), \
    (__attribute__((address_space(3))) void*)(lp), 16, 0, 0)

static __device__ __forceinline__ float  wredf(float x){
  #pragma unroll
  for (int o=32;o;o>>=1) x += __shfl_down(x,o);
  return x;
}
static __device__ __forceinline__ double wredd(double x){
  #pragma unroll
  for (int o=32;o;o>>=1) x += __shfl_down(x,o);
  return x;
}

// ================= PCA (multi-kernel; grid.sync measured ~60us/sync on MI355X -> relaunch instead) ====
// Column sums of A -> 8 partial buffers. 1024 blocks, 16 rows/block (4/wave).
__global__ __launch_bounds__(256) void kP0(const float* __restrict__ A, double* __restrict__ meanp){
  __shared__ double red[4][12][64];
  int lane = threadIdx.x & 63, w = threadIdx.x >> 6;
  int rbase = blockIdx.x*16 + w*4;
  double acc[12];
  #pragma unroll
  for (int j=0;j<12;j++) acc[j]=0.0;
  for (int i=0;i<4;i++){
    const float* Ar = A + (size_t)(rbase+i)*DBB;
    #pragma unroll
    for (int j=0;j<12;j++) acc[j] += (double)Ar[j*64+lane];
  }
  #pragma unroll
  for (int j=0;j<12;j++) red[w][j][lane] = acc[j];
  __syncthreads();
  double* dst = meanp + (size_t)(blockIdx.x&7)*768;
  for (int cc=threadIdx.x; cc<768; cc+=256){
    int j = cc>>6, l = cc&63;
    atomicAdd(&dst[cc], red[0][j][l]+red[1][j][l]+red[2][j][l]+red[3][j][l]);
  }
}

// reduce the 8 colsum partials once -> final mean vector
__global__ __launch_bounds__(256) void kRedM(const double* __restrict__ meanp, double* __restrict__ msf){
  for (int cc=threadIdx.x; cc<768; cc+=256){
    double s=0.0;
    #pragma unroll
    for (int p=0;p<8;p++) s += meanp[p*768+cc];
    msf[cc] = s * (1.0/16384.0);
  }
}

// one un-normalized power-iteration step: y_partials += Ac^T (Ac x). xp==nullptr -> x = const.
// Un-normalized is direction-equivalent (f64 iterates peak ~1e44 << f64 range; Us scale-invariant).
__global__ __launch_bounds__(256) void kPIter(const float* __restrict__ A, const double* __restrict__ msf,
                                              const double* __restrict__ xp, double* __restrict__ y){
  __shared__ double vs[768], ms[768];
  __shared__ double red[4][12][64];
  for (int cc=threadIdx.x; cc<768; cc+=256){
    ms[cc] = msf[cc];
    if (xp){
      double sv=0.0;
      #pragma unroll
      for (int p=0;p<8;p++) sv += xp[p*768+cc];
      vs[cc] = sv;
    } else {
      vs[cc] = 1.0/sqrt(768.0);
    }
  }
  __syncthreads();
  int lane = threadIdx.x & 63, w = threadIdx.x >> 6;
  int rbase = blockIdx.x*16 + w*4;
  double acc[12];
  #pragma unroll
  for (int j=0;j<12;j++) acc[j]=0.0;
  for (int i=0;i<4;i++){
    const float* Ar = A + (size_t)(rbase+i)*DBB;
    double ad[12]; double wp = 0.0;
    #pragma unroll
    for (int j=0;j<12;j++){ int c=j*64+lane; ad[j] = (double)Ar[c]-ms[c]; wp += ad[j]*vs[c]; }
    wp = wredd(wp); wp = __shfl(wp, 0);
    #pragma unroll
    for (int j=0;j<12;j++) acc[j] += wp*ad[j];
  }
  #pragma unroll
  for (int j=0;j<12;j++) red[w][j][lane] = acc[j];
  __syncthreads();
  double* dst = y + (size_t)(blockIdx.x&7)*768;
  for (int cc=threadIdx.x; cc<768; cc+=256){
    int j = cc>>6, l = cc&63;
    atomicAdd(&dst[cc], red[0][j][l]+red[1][j][l]+red[2][j][l]+red[3][j][l]);
  }
}

// u = Ac v   (v summed from 8 partials)
__global__ __launch_bounds__(256) void kPU(const float* __restrict__ A, const double* __restrict__ msf,
                                           const double* __restrict__ vp, double* __restrict__ u){
  __shared__ double vs[768], ms[768];
  for (int cc=threadIdx.x; cc<768; cc+=256){
    ms[cc] = msf[cc];
    double sv=0.0;
    #pragma unroll
    for (int p=0;p<8;p++) sv += vp[p*768+cc];
    vs[cc] = sv;
  }
  __syncthreads();
  int lane=threadIdx.x&63, w=threadIdx.x>>6;
  int rbase = blockIdx.x*16 + w*4;
  for (int i=0;i<4;i++){
    const float* Ar = A + (size_t)(rbase+i)*DBB;
    double wp=0.0;
    #pragma unroll
    for (int j=0;j<12;j++){ int c=j*64+lane; wp += ((double)Ar[c]-ms[c])*vs[c]; }
    wp = wredd(wp);
    if (lane==0) u[rbase+i] = wp;
  }
}

// fused global minmax + pseudo-gt + Bk (single block)
__global__ __launch_bounds__(1024) void kFin(const double* __restrict__ u, const int* __restrict__ gt,
      float* __restrict__ outPG, int* __restrict__ gtseg, int* __restrict__ Bk){
  __shared__ double smn[16], smx[16];
  __shared__ double sres[2];
  int t = threadIdx.x;
  double mn=1e300, mx=-1e300;
  for (int k=0;k<16;k++){ double x=u[k*1024+t]; mn=fmin(mn,x); mx=fmax(mx,x); }
  #pragma unroll
  for (int o=32;o;o>>=1){ mn=fmin(mn,__shfl_down(mn,o)); mx=fmax(mx,__shfl_down(mx,o)); }
  if ((t&63)==0){ smn[t>>6]=mn; smx[t>>6]=mx; }
  __syncthreads();
  if (t==0){
    for (int i=1;i<16;i++){ mn=fmin(mn,smn[i]); mx=fmax(mx,smx[i]); }
    sres[0]=mn; sres[1]=mx;
  }
  __syncthreads();
  mn=sres[0]; mx=sres[1];
  double inv = 1.0/(mx-mn);
  for (int k=0;k<16;k++){
    int n = k*1024 + t;           // image index = k for all threads
    int c0 = gt[k];
    double us = (u[n]-mn)*inv;
    int g = (us < 0.5) ? c0 : 200;
    outPG[n] = (float)g;
    gtseg[n] = g;
    unsigned long long b0 = __ballot(g==c0);
    unsigned long long b1 = __ballot(g==200);
    if ((t&63)==0){
      atomicAdd(&Bk[c0], (int)__popcll(b0));
      atomicAdd(&Bk[200], (int)__popcll(b1));
    }
  }
}

// ================= prep: W f32->f16 (blocks 0..383) + proto l2-normalize (blocks 384..895) =================
__global__ __launch_bounds__(256) void kPrep(const float* __restrict__ Wp, _Float16* __restrict__ W16,
    const float* __restrict__ PR, float* __restrict__ Pn, _Float16* __restrict__ P16){
  int b = blockIdx.x;
  if (b < 384){
    int i = b*256 + threadIdx.x;
    float4 vv = ((const float4*)Wp)[i];
    half4v h; h[0]=(_Float16)vv.x; h[1]=(_Float16)vv.y; h[2]=(_Float16)vv.z; h[3]=(_Float16)vv.w;
    ((half4v*)W16)[i] = h;
    return;
  }
  int w=threadIdx.x>>6, lane=threadIdx.x&63;
  int km = (b-384)*4 + w;
  if (km >= KM){
    if (km < KMP){
      half8 z;
      #pragma unroll
      for (int i=0;i<8;i++) z[i]=(_Float16)0.0f;
      *(half8*)(P16 + (size_t)km*DD + lane*8) = z;
    }
    return;
  }
  const float* r = PR + (size_t)km*DD + lane*8;
  float4 a = *(const float4*)r, b2 = *(const float4*)(r+4);
  float x[8] = {a.x,a.y,a.z,a.w,b2.x,b2.y,b2.z,b2.w};
  float ss=0;
  #pragma unroll
  for (int i=0;i<8;i++) ss += x[i]*x[i];
  ss = __shfl(wredf(ss),0);
  float nrm = fmaxf(sqrtf(ss), 1e-12f);
  float* pw = Pn + (size_t)km*DD + lane*8;
  half8 h;
  #pragma unroll
  for (int i=0;i<8;i++){ float vv = x[i]/nrm; pw[i]=vv; h[i]=(_Float16)vv; }
  *(half8*)(P16 + (size_t)km*DD + lane*8) = h;
}

// ================= GEMM1: C16[16384,512] = f16( A_f32 @ W16^T + b ) =================
__global__ __launch_bounds__(256) void gemm1(const float* __restrict__ Af, const _Float16* __restrict__ Bm,
    _Float16* __restrict__ Ch, const float* __restrict__ bias){
  __shared__ __align__(16) char As[128*128];
  __shared__ __align__(16) char Bs[128*128];
  const int tid = threadIdx.x;
  const int lane = tid & 63, w = tid >> 6;
  const int wr = w >> 1, wc = w & 1;
  const int lrow = lane & 15, kg = lane >> 4;
  const int id = blockIdx.x;
  const int xcd = id & 7, pos = id >> 3;
  const int m0 = ((xcd<<4) | (pos>>2)) * 128;
  const int n0 = (pos & 3) * 128;

  f32x4 acc[4][4];
  #pragma unroll
  for (int i=0;i<4;i++)
    #pragma unroll
    for (int j=0;j<4;j++){ f32x4 z = {0.f,0.f,0.f,0.f}; acc[i][j]=z; }

  for (int k0 = 0; k0 < DBB; k0 += 64){
    #pragma unroll
    for (int i=0;i<4;i++){
      int slot = (i*4 + w)*64 + lane;
      int r = slot >> 3, c = slot & 7;
      int cs = c ^ (r & 7);
      GLDS16(Bm + (size_t)(n0+r)*DBB + k0 + cs*8, Bs + (i*4+w)*1024);
    }
    #pragma unroll
    for (int i=0;i<8;i++){
      int slot = i*256 + tid;
      int r = slot >> 4, c4 = slot & 15;
      float4 v = *(const float4*)(Af + (size_t)(m0+r)*DBB + k0 + c4*4);
      half4v h; h[0]=(_Float16)v.x; h[1]=(_Float16)v.y; h[2]=(_Float16)v.z; h[3]=(_Float16)v.w;
      *(half4v*)(As + r*128 + (((c4>>1)^(r&7))<<4) + (c4&1)*8) = h;
    }
    __syncthreads();
    #pragma unroll
    for (int h=0; h<2; h++){
      half8 af[4], bf[4];
      #pragma unroll
      for (int mi=0;mi<4;mi++){
        int ar = wr*64 + mi*16 + lrow;
        af[mi] = *(const half8*)(As + ar*128 + (((h*4+kg) ^ (ar&7))<<4));
      }
      #pragma unroll
      for (int nj=0;nj<4;nj++){
        int br = wc*64 + nj*16 + lrow;
        bf[nj] = *(const half8*)(Bs + br*128 + (((h*4+kg) ^ (br&7))<<4));
      }
      #pragma unroll
      for (int mi=0;mi<4;mi++)
        #pragma unroll
        for (int nj=0;nj<4;nj++)
          acc[mi][nj] = __builtin_amdgcn_mfma_f32_16x16x32_f16(af[mi], bf[nj], acc[mi][nj], 0,0,0);
    }
    __syncthreads();
  }
  #pragma unroll
  for (int mi=0;mi<4;mi++){
    int gr = m0 + wr*64 + mi*16 + kg*4;
    #pragma unroll
    for (int nj=0;nj<4;nj++){
      int gc = n0 + wc*64 + nj*16 + lrow;
      float bv = bias[gc];
      #pragma unroll
      for (int r2=0;r2<4;r2++)
        Ch[(size_t)(gr+r2)*DD + gc] = (_Float16)(acc[mi][nj][r2] + bv);
    }
  }
}

// ================= GEMM2: PL[16384,2010] = _c @ protos^T =================
__global__ __launch_bounds__(256) void gemm2(const _Float16* __restrict__ Am, const _Float16* __restrict__ Bm,
    float* __restrict__ Cf){
  __shared__ __align__(16) char As[128*128];
  __shared__ __align__(16) char Bs[128*128];
  const int tid = threadIdx.x;
  const int lane = tid & 63, w = tid >> 6;
  const int wr = w >> 1, wc = w & 1;
  const int lrow = lane & 15, kg = lane >> 4;
  const int id = blockIdx.x;
  const int xcd = id & 7, pos = id >> 3;
  const int m0 = ((xcd<<4) | (pos>>4)) * 128;
  const int n0 = (pos & 15) * 128;

  f32x4 acc[4][4];
  #pragma unroll
  for (int i=0;i<4;i++)
    #pragma unroll
    for (int j=0;j<4;j++){ f32x4 z = {0.f,0.f,0.f,0.f}; acc[i][j]=z; }

  for (int k0 = 0; k0 < DD; k0 += 64){
    #pragma unroll
    for (int i=0;i<4;i++){
      int slot = (i*4 + w)*64 + lane;
      int r = slot >> 3, c = slot & 7;
      int cs = c ^ (r & 7);
      GLDS16(Am + (size_t)(m0+r)*DD + k0 + cs*8, As + (i*4+w)*1024);
      GLDS16(Bm + (size_t)(n0+r)*DD + k0 + cs*8, Bs + (i*4+w)*1024);
    }
    __syncthreads();
    #pragma unroll
    for (int h=0; h<2; h++){
      half8 af[4], bf[4];
      #pragma unroll
      for (int mi=0;mi<4;mi++){
        int ar = wr*64 + mi*16 + lrow;
        af[mi] = *(const half8*)(As + ar*128 + (((h*4+kg) ^ (ar&7))<<4));
      }
      #pragma unroll
      for (int nj=0;nj<4;nj++){
        int br = wc*64 + nj*16 + lrow;
        bf[nj] = *(const half8*)(Bs + br*128 + (((h*4+kg) ^ (br&7))<<4));
      }
      #pragma unroll
      for (int mi=0;mi<4;mi++)
        #pragma unroll
        for (int nj=0;nj<4;nj++)
          acc[mi][nj] = __builtin_amdgcn_mfma_f32_16x16x32_f16(af[mi], bf[nj], acc[mi][nj], 0,0,0);
    }
    __syncthreads();
  }
  #pragma unroll
  for (int mi=0;mi<4;mi++){
    int gr = m0 + wr*64 + mi*16 + kg*4;
    #pragma unroll
    for (int nj=0;nj<4;nj++){
      int gc = n0 + wc*64 + nj*16 + lrow;
      if (gc < KM){
        #pragma unroll
        for (int r2=0;r2<4;r2++)
          Cf[(size_t)(gr+r2)*KM + gc] = acc[mi][nj][r2];
      }
    }
  }
}

// ================= LN + l2 normalize (in-place on C16) =================
__global__ __launch_bounds__(256) void kLNl2n(_Float16* __restrict__ C16,
      const float* __restrict__ fg, const float* __restrict__ fb){
  int w=threadIdx.x>>6, lane=threadIdx.x&63;
  int n = blockIdx.x*4 + w;
  _Float16* row = C16 + (size_t)n*DD + lane*8;
  half8 h = *(const half8*)row;
  float x[8];
  #pragma unroll
  for (int i=0;i<8;i++) x[i] = (float)h[i];
  float s=0;
  #pragma unroll
  for (int i=0;i<8;i++) s += x[i];
  float mu = __shfl(wredf(s),0)/512.f;
  float q=0;
  #pragma unroll
  for (int i=0;i<8;i++){ float d=x[i]-mu; q+=d*d; }
  float var = __shfl(wredf(q),0)/512.f;
  float inv = 1.f/sqrtf(var+1e-5f);
  float4 g0 = *(const float4*)(fg+lane*8), g1 = *(const float4*)(fg+lane*8+4);
  float4 b0 = *(const float4*)(fb+lane*8), b1 = *(const float4*)(fb+lane*8+4);
  float gg[8] = {g0.x,g0.y,g0.z,g0.w,g1.x,g1.y,g1.z,g1.w};
  float bb[8] = {b0.x,b0.y,b0.z,b0.w,b1.x,b1.y,b1.z,b1.w};
  float y[8]; float ss=0;
  #pragma unroll
  for (int i=0;i<8;i++){ y[i] = (x[i]-mu)*inv*gg[i]+bb[i]; ss += y[i]*y[i]; }
  float nrm = fmaxf(sqrtf(__shfl(wredf(ss),0)), 1e-12f);
  half8 o;
  #pragma unroll
  for (int i=0;i<8;i++) o[i] = (_Float16)(y[i]/nrm);
  *(half8*)row = o;
}

// ===== fused per-class max + mask LN + pred + transpose-out + sinkhorn Qd/row0 partials =====
__global__ __launch_bounds__(256) void kMaxSK(const float* __restrict__ PL, const float* __restrict__ mg,
    const float* __restrict__ mb, const int* __restrict__ gtseg, const int* __restrict__ gt,
    float* __restrict__ outseg, int* __restrict__ corr, float* __restrict__ Qd, float* __restrict__ row16){
  __shared__ float rowb[4][2016];
  __shared__ float tile[32][205];
  int w=threadIdx.x>>6, lane=threadIdx.x&63;
  int n0 = blockIdx.x*32;
  int b = n0>>10, hw0 = n0&1023;
  int c0 = gt[b];
  float p0=0.f, p1=0.f;                 // lanes 0..9: per-m rowsum partials
  for (int g8=0; g8<8; ++g8){
    int n = n0 + g8*4 + w;
    int g = gtseg[n];
    const float* src = PL + (size_t)n*KM;
    for (int j2=lane;j2<1005;j2+=64)
      *(float2*)(&rowb[w][j2*2]) = *(const float2*)(src + j2*2);
    // wave-local staging: no cross-wave sharing, no barrier needed
    float xv[4]; int ncl=0;
    for (int c=lane;c<KC;c+=64){
      float mx = rowb[w][c*10];
      #pragma unroll
      for (int m=1;m<10;m++) mx = fmaxf(mx, rowb[w][c*10+m]);
      xv[ncl++] = mx;
    }
    float ps=0;
    for (int i=0;i<ncl;i++) ps += xv[i];
    float mu = __shfl(wredf(ps),0)*(1.f/201.f);
    float pv=0;
    for (int i=0;i<ncl;i++){ float d=xv[i]-mu; pv+=d*d; }
    float var = __shfl(wredf(pv),0)*(1.f/201.f);
    float inv = 1.f/sqrtf(var+1e-5f);
    float bv = -3.0e38f; int bi = 1<<30;
    int lr = g8*4 + w;
    ncl = 0;
    for (int c=lane;c<KC;c+=64){
      float o = (xv[ncl]-mu)*inv*mg[c]+mb[c]; ncl++;
      tile[lr][c] = o;
      if (o > bv){ bv=o; bi=c; }
    }
    #pragma unroll
    for (int o2=32;o2;o2>>=1){
      float ov = __shfl_down(bv,o2); int oi = __shfl_down(bi,o2);
      if (ov>bv || (ov==bv && oi<bi)){ bv=ov; bi=oi; }
    }
    if (lane==0) corr[n] = (bi==gtseg[n]) ? 1 : 0;
    // sinkhorn: Q = exp(masks[n,:,g]/eps); g is c0 or 200 by construction
    if (lane < 10){
      float e = expf(rowb[w][g*10+lane]*20.f);
      Qd[(size_t)n*10+lane] = e;
      if (g==c0) p0 += e; else p1 += e;
    }
  }
  if (lane < 10){
    float* rp = row16 + (size_t)(blockIdx.x&15)*2016 + lane*KC;
    atomicAdd(&rp[c0], p0);
    atomicAdd(&rp[200], p1);
  }
  __syncthreads();
  for (int idx=threadIdx.x; idx<KC*32; idx+=256){
    int c = idx>>5, j = idx&31;
    outseg[(((size_t)b*KC+c)<<10) + hw0 + j] = tile[j][c];
  }
}

// one sinkhorn iteration; rin has rin_parts partial buffers of stride 2016
__global__ __launch_bounds__(256) void kSKpass(float* __restrict__ Qd, const int* __restrict__ gtseg,
      const int* __restrict__ gt, const float* __restrict__ rin, int rin_parts,
      float* __restrict__ rout, const int* __restrict__ Bk){
  __shared__ float rin2[10][2];
  __shared__ double part[4][10][2];
  int n = blockIdx.x*256+threadIdx.x;
  int c0 = gt[blockIdx.x>>2];
  if (threadIdx.x < 20){
    int m = threadIdx.x>>1, cl = threadIdx.x&1;
    int cls = cl?200:c0;
    float s=0;
    for (int p=0;p<rin_parts;p++) s += rin[(size_t)p*2016 + m*KC + cls];
    rin2[m][cl]=s;
  }
  __syncthreads();
  int g = gtseg[n];
  int cl = (g==200)?1:0;
  double q[10]; double col=0.0;
  #pragma unroll
  for (int m=0;m<10;m++){
    double r = (double)rin2[m][cl];
    double t = (double)Qd[(size_t)n*10+m];
    if (r>0.0) t = t/r;
    t = t/10.0;
    q[m]=t; col+=t;
  }
  double cs = (col>0.0)? col : 1.0;
  int bk = Bk[g];
  double bs = (bk>0)? (double)bk : 1.0;
  double inv = 1.0/(cs*bs);
  int w=threadIdx.x>>6, lane=threadIdx.x&63;
  #pragma unroll
  for (int m=0;m<10;m++){
    double t = q[m]*inv;
    Qd[(size_t)n*10+m] = (float)t;
    double p0 = (g==c0)? t:0.0;
    double p1 = (g==200)? t:0.0;
    p0=wredd(p0); p1=wredd(p1);
    if (lane==0){ part[w][m][0]=p0; part[w][m][1]=p1; }
  }
  __syncthreads();
  if (threadIdx.x < 20){
    int m = threadIdx.x>>1, cl2 = threadIdx.x&1;
    double t = part[0][m][cl2]+part[1][m][cl2]+part[2][m][cl2]+part[3][m][cl2];
    atomicAdd(&rout[m*KC + (cl2?200:c0)], (float)t);
  }
}

// fused final argmax + proto_target write + EMA accumulation (wave per pixel)
__global__ __launch_bounds__(256) void kSKEMA(const float* __restrict__ Qd, const int* __restrict__ gtseg,
      const float* __restrict__ r5, const int* __restrict__ corr, const _Float16* __restrict__ C16,
      float* __restrict__ outPT, float* __restrict__ fproto, int* __restrict__ ncnt){
  int w=threadIdx.x>>6, lane=threadIdx.x&63;
  int n = blockIdx.x*4+w;
  int g = gtseg[n];
  float tv = -1.0f;
  if (lane<10){
    float r = r5[lane*KC+g];
    float t = Qd[(size_t)n*10+lane];
    if (r>0.f) t = t/r;
    tv = t*0.1f;
  }
  float bv = tv; int bi = lane;
  #pragma unroll
  for (int o=8;o;o>>=1){
    float ov = __shfl_down(bv,o); int oi = __shfl_down(bi,o);
    if (ov>bv || (ov==bv && oi<bi)){ bv=ov; bi=oi; }
  }
  bi = __shfl(bi, 0);
  if (lane==0) outPT[n] = (float)(bi + 10*g);
  if (corr[n]){
    half8 hc = *(const half8*)(C16 + (size_t)n*DD + lane*8);
    float* dst = fproto + ((size_t)g*10+bi)*DD + lane*8;
    #pragma unroll
    for (int i=0;i<8;i++) atomicAdd(dst+i, (float)hc[i]);
    if (lane==0) atomicAdd(&ncnt[g*10+bi], 1);
  }
}

__global__ __launch_bounds__(256) void kEMAfin(const float* __restrict__ fproto, const int* __restrict__ ncnt,
     const float* __restrict__ Pn, float* __restrict__ outNP){
  int w=threadIdx.x>>6, lane=threadIdx.x&63;
  int km = blockIdx.x*4+w;
  if (km>=KM) return;
  const float* fr = fproto + (size_t)km*DD + lane*8;
  float fp[8]; float ss=0;
  #pragma unroll
  for (int i=0;i<8;i++){ fp[i]=fr[i]; ss+=fp[i]*fp[i]; }
  float n1 = fmaxf(sqrtf(__shfl(wredf(ss),0)), 1e-12f);
  int cnt = ncnt[km];
  const float* pr = Pn + (size_t)km*DD + lane*8;
  float t[8]; float s2=0;
  #pragma unroll
  for (int i=0;i<8;i++){
    float pv = pr[i];
    float tv = cnt ? (0.999f*pv + 0.001f*(fp[i]/n1)) : pv;
    t[i]=tv; s2+=tv*tv;
  }
  float n2 = fmaxf(sqrtf(__shfl(wredf(s2),0)), 1e-12f);
  float* dst = outNP + (size_t)km*DD + lane*8;
  #pragma unroll
  for (int i=0;i<8;i++) dst[i] = t[i]/n2;
}

// ================= launch =================
extern "C" void kernel_launch(void* const* d_in, const int* in_sizes, int n_in,
                              void* d_out, int out_size, void* d_ws, size_t ws_size,
                              hipStream_t stream) {
  const float* A   = (const float*)d_in[0];
  const int*   gt  = (const int*)d_in[1];
  const float* Wp  = (const float*)d_in[2];
  const float* pb  = (const float*)d_in[3];
  const float* fg  = (const float*)d_in[4];
  const float* fb  = (const float*)d_in[5];
  const float* mg  = (const float*)d_in[6];
  const float* mb  = (const float*)d_in[7];
  const float* PR  = (const float*)d_in[8];
  float* out = (float*)d_out;
  char* ws = (char*)d_ws;

  double* meanp  = (double*)(ws+OFF_MEANP);
  double* xch    = (double*)(ws+OFF_XCH);
  float*  row16  = (float*)(ws+OFF_ROW16);
  float*  row3   = (float*)(ws+OFF_ROW3);
  float*  row5   = (float*)(ws+OFF_ROW5);
  int*    Bk     = (int*)(ws+OFF_BK);
  int*    ncnt   = (int*)(ws+OFF_NCNT);
  float*  fproto = (float*)(ws+OFF_FPROTO);
  double* msf    = (double*)(ws+OFF_MSF);
  int*    gtseg  = (int*)(ws+OFF_GTSEG);
  int*    corr   = (int*)(ws+OFF_CORR);
  double* u      = (double*)(ws+OFF_U);
  float*  Pn     = (float*)(ws+OFF_PN);
  _Float16* P16  = (_Float16*)(ws+OFF_P16);
  _Float16* C16  = (_Float16*)(ws+OFF_C16);
  float*  Qd     = (float*)(ws+OFF_QD);
  _Float16* W16  = (_Float16*)(ws+OFF_W16);

  // single memset: all atomic accumulators
  hipMemsetAsync(ws, 0, ZTOTAL, stream);

  // ---- PCA pseudo-gt (multi-kernel; un-normalized f64 power iteration) ----
  kP0<<<1024,256,0,stream>>>(A, meanp);
  kRedM<<<1,256,0,stream>>>(meanp, msf);
  for (int t=0;t<10;t++){
    const double* xp = (t==0)? nullptr : (xch + (size_t)(t-1)*8*768);
    kPIter<<<1024,256,0,stream>>>(A, msf, xp, xch + (size_t)t*8*768);
  }
  kPU<<<1024,256,0,stream>>>(A, msf, xch + (size_t)9*8*768, u);
  kFin<<<1,1024,0,stream>>>(u, gt, out+OUT_PG, gtseg, Bk);

  // ---- prep: W conv + proto normalize ----
  kPrep<<<896,256,0,stream>>>(Wp, W16, PR, Pn, P16);

  // ---- GEMM1 (f32 A, fused convert) + LN+l2n ----
  gemm1<<<512,256,0,stream>>>(A, W16, C16, pb);
  kLNl2n<<<4096,256,0,stream>>>(C16, fg, fb);

  // ---- GEMM2: proto_logits ----
  gemm2<<<2048,256,0,stream>>>(C16, P16, out+OUT_PL);

  // ---- fused max/LN/pred/transpose + sinkhorn row0 ----
  kMaxSK<<<512,256,0,stream>>>(out+OUT_PL, mg, mb, gtseg, gt, out+OUT_SEG, corr, Qd, row16);

  // ---- sinkhorn passes + fused argmax/EMA ----
  kSKpass<<<64,256,0,stream>>>(Qd, gtseg, gt, row16, 16, row3, Bk);
  kSKpass<<<64,256,0,stream>>>(Qd, gtseg, gt, row3, 1, row5, Bk);
  kSKEMA<<<4096,256,0,stream>>>(Qd, gtseg, row5, corr, C16, out+OUT_PT, fproto, ncnt);

  // ---- EMA finalize ----
  kEMAfin<<<503,256,0,stream>>>(fproto, ncnt, Pn, out+OUT_NP);
}